// Round 2
// baseline (74680.200 us; speedup 1.0000x reference)
//
#include <hip/hip_runtime.h>

#define BB 256
#define HH 1024
#define EE 256
#define VV 28
#define ZZ 1024
#define TT 512
#define G3 3072
#define NTHR 256
#define TOKBASE (BB * TT * VV)

#define BM 64
#define BN 64
#define KT 32

typedef float f4 __attribute__((ext_vector_type(4)));

// Persistent state (fully rewritten every call; deterministic).
__device__ __align__(16) float g_h0[2][BB][HH];
__device__ __align__(16) float g_h1[2][BB][HH];
__device__ __align__(16) float g_gh0[2][BB][G3];
__device__ __align__(16) float g_gh1[2][BB][G3];
__device__ __align__(16) float g_gi1[BB][G3];
__device__ __align__(16) float g_P0[VV][G3];
__device__ int g_tok[2][BB];

// ---- threefry2x32, JAX-exact (20 rounds) ----
__device__ __forceinline__ uint2 tf2x32(unsigned k0, unsigned k1,
                                        unsigned x0, unsigned x1) {
  unsigned ks2 = k0 ^ k1 ^ 0x1BD11BDAu;
  unsigned ksl[3] = {k0, k1, ks2};
  x0 += k0; x1 += k1;
#pragma unroll
  for (int g = 0; g < 5; ++g) {
    const int r0 = (g & 1) ? 17 : 13;
    const int r1 = (g & 1) ? 29 : 15;
    const int r2 = (g & 1) ? 16 : 26;
    const int r3 = (g & 1) ? 24 : 6;
    x0 += x1; x1 = (x1 << r0) | (x1 >> (32 - r0)); x1 ^= x0;
    x0 += x1; x1 = (x1 << r1) | (x1 >> (32 - r1)); x1 ^= x0;
    x0 += x1; x1 = (x1 << r2) | (x1 >> (32 - r2)); x1 ^= x0;
    x0 += x1; x1 = (x1 << r3) | (x1 >> (32 - r3)); x1 ^= x0;
    x0 += ksl[(g + 1) % 3];
    x1 += ksl[(g + 2) % 3] + (unsigned)(g + 1);
  }
  return make_uint2(x0, x1);
}

__device__ __forceinline__ float sigf(float x) {
  return 1.0f / (1.0f + expf(-x));
}

__device__ __forceinline__ float gru_h(float i_r, float h_r, float i_z, float h_z,
                                       float i_n, float h_n, float hprev) {
  float r  = sigf(i_r + h_r);
  float zg = sigf(i_z + h_z);
  float n  = tanhf(i_n + r * h_n);
  return (1.0f - zg) * n + zg * hprev;
}

// C[m][n] = sum_k A[m][k] * W[n][k] + bias[n]; mode 1 applies tanh.
// Pointers pre-offset to tile origin. 64x64 tile, K-chunks of 32, 256 thr.
__device__ __forceinline__ void gemm_unit(
    const float* __restrict__ At, int lda, int rows_valid,
    const float* __restrict__ Wt, int ldw,
    const float* __restrict__ bias,
    float* __restrict__ Ct, int ldc,
    int K, int mode,
    float (&As)[BM][KT + 4], float (&Ws)[KT][BN + 4]) {
  const int tid = threadIdx.x;
  const int tx = tid & 15, ty = tid >> 4;
  f4 acc0 = {0.f, 0.f, 0.f, 0.f};
  f4 acc1 = {0.f, 0.f, 0.f, 0.f};
  f4 acc2 = {0.f, 0.f, 0.f, 0.f};
  f4 acc3 = {0.f, 0.f, 0.f, 0.f};

  for (int kb = 0; kb < K; kb += KT) {
#pragma unroll
    for (int l = 0; l < 2; ++l) {
      int f = tid + l * NTHR;
      int r = f >> 3, kq = (f & 7) << 2;
      f4 v = {0.f, 0.f, 0.f, 0.f};
      if (r < rows_valid) v = *(const f4*)(At + r * lda + kb + kq);
      *(f4*)&As[r][kq] = v;
    }
#pragma unroll
    for (int l = 0; l < 2; ++l) {
      int f = tid + l * NTHR;
      int nr = f >> 3, kq = (f & 7) << 2;
      f4 v = *(const f4*)(Wt + nr * ldw + kb + kq);
      Ws[kq + 0][nr] = v[0];
      Ws[kq + 1][nr] = v[1];
      Ws[kq + 2][nr] = v[2];
      Ws[kq + 3][nr] = v[3];
    }
    __syncthreads();
#pragma unroll
    for (int kk = 0; kk < KT; kk += 4) {
      f4 a0 = *(const f4*)&As[(ty << 2) + 0][kk];
      f4 a1 = *(const f4*)&As[(ty << 2) + 1][kk];
      f4 a2 = *(const f4*)&As[(ty << 2) + 2][kk];
      f4 a3 = *(const f4*)&As[(ty << 2) + 3][kk];
      f4 b0 = *(const f4*)&Ws[kk + 0][tx << 2];
      f4 b1 = *(const f4*)&Ws[kk + 1][tx << 2];
      f4 b2 = *(const f4*)&Ws[kk + 2][tx << 2];
      f4 b3 = *(const f4*)&Ws[kk + 3][tx << 2];
      acc0 += b0 * a0[0]; acc0 += b1 * a0[1]; acc0 += b2 * a0[2]; acc0 += b3 * a0[3];
      acc1 += b0 * a1[0]; acc1 += b1 * a1[1]; acc1 += b2 * a1[2]; acc1 += b3 * a1[3];
      acc2 += b0 * a2[0]; acc2 += b1 * a2[1]; acc2 += b2 * a2[2]; acc2 += b3 * a2[3];
      acc3 += b0 * a3[0]; acc3 += b1 * a3[1]; acc3 += b2 * a3[2]; acc3 += b3 * a3[3];
    }
    __syncthreads();
  }

  f4 accs[4] = {acc0, acc1, acc2, acc3};
#pragma unroll
  for (int i = 0; i < 4; ++i) {
    int r = (ty << 2) + i;
    if (r < rows_valid) {
#pragma unroll
      for (int j = 0; j < 4; ++j) {
        int c = (tx << 2) + j;
        float v = accs[i][j] + bias[c];
        if (mode == 1) v = tanhf(v);
        Ct[r * ldc + c] = v;
      }
    }
  }
}

// Setup 1: h-init GEMM (128 tiles), P0 = emb@w_ih0^T (48 tiles), tok init.
__global__ __launch_bounds__(NTHR) void k_setup1(
    const float* __restrict__ z, const float* __restrict__ w_zh,
    const float* __restrict__ b_zh, const float* __restrict__ emb,
    const float* __restrict__ w_ih0, const float* __restrict__ b_ih0) {
  __shared__ __align__(16) float As[BM][KT + 4];
  __shared__ __align__(16) float Ws[KT][BN + 4];
  const int bid = blockIdx.x;
  if (bid < 128) {
    int m0 = (bid >> 5) * BM;
    int n0 = (bid & 31) * BN;
    float* Cb;
    int col;
    if (n0 < HH) { Cb = &g_h0[0][0][0]; col = n0; }
    else         { Cb = &g_h1[0][0][0]; col = n0 - HH; }
    gemm_unit(z + m0 * ZZ, ZZ, BM, w_zh + n0 * ZZ, ZZ, b_zh + n0,
              Cb + m0 * HH + col, HH, ZZ, 1, As, Ws);
  } else if (bid < 176) {
    int n0 = (bid - 128) * BN;
    gemm_unit(emb, EE, VV, w_ih0 + n0 * EE, EE, b_ih0 + n0,
              &g_P0[0][0] + n0, G3, EE, 0, As, Ws);
  } else {
    if (threadIdx.x < BB) g_tok[0][threadIdx.x] = 1;  // SOS_IDX
  }
}

// Setup 2: gh0[0] = h0@w_hh0^T + b ; gh1[0] = h1@w_hh1^T + b  (384 tiles)
__global__ __launch_bounds__(NTHR) void k_setup2(
    const float* __restrict__ w_hh0, const float* __restrict__ b_hh0,
    const float* __restrict__ w_hh1, const float* __restrict__ b_hh1) {
  __shared__ __align__(16) float As[BM][KT + 4];
  __shared__ __align__(16) float Ws[KT][BN + 4];
  const int bid = blockIdx.x;
  int u = (bid < 192) ? bid : bid - 192;
  int m0 = (u / 48) * BM, n0 = (u % 48) * BN;
  if (bid < 192) {
    gemm_unit(&g_h0[0][0][0] + m0 * HH, HH, BM, w_hh0 + n0 * HH, HH, b_hh0 + n0,
              &g_gh0[0][0][0] + m0 * G3 + n0, G3, HH, 0, As, Ws);
  } else {
    gemm_unit(&g_h1[0][0][0] + m0 * HH, HH, BM, w_hh1 + n0 * HH, HH, b_hh1 + n0,
              &g_gh1[0][0][0] + m0 * G3 + n0, G3, HH, 0, As, Ws);
  }
}

// GRU layer-0 elementwise: one batch row per block.
__global__ __launch_bounds__(NTHR) void k_gate0(int p) {
  const int q = p ^ 1;
  const int b = blockIdx.x;
  const int j = threadIdx.x << 2;
  const float* __restrict__ gi = g_P0[g_tok[p][b]];
  const float* __restrict__ gh = g_gh0[p][b];
  f4 ir = *(const f4*)&gi[j];
  f4 iz = *(const f4*)&gi[j + HH];
  f4 in_ = *(const f4*)&gi[j + 2 * HH];
  f4 hr = *(const f4*)&gh[j];
  f4 hz = *(const f4*)&gh[j + HH];
  f4 hn = *(const f4*)&gh[j + 2 * HH];
  f4 hp = *(const f4*)&g_h0[p][b][j];
  f4 ho;
#pragma unroll
  for (int c = 0; c < 4; ++c)
    ho[c] = gru_h(ir[c], hr[c], iz[c], hz[c], in_[c], hn[c], hp[c]);
  *(f4*)&g_h0[q][b][j] = ho;
}

// gi1 = h0n @ w_ih1^T + b_ih1   (192 tiles)
__global__ __launch_bounds__(NTHR) void k_gi1(
    int p, const float* __restrict__ w_ih1, const float* __restrict__ b_ih1) {
  __shared__ __align__(16) float As[BM][KT + 4];
  __shared__ __align__(16) float Ws[KT][BN + 4];
  const int q = p ^ 1;
  int m0 = ((int)blockIdx.x / 48) * BM, n0 = ((int)blockIdx.x % 48) * BN;
  gemm_unit(&g_h0[q][0][0] + m0 * HH, HH, BM, w_ih1 + n0 * HH, HH, b_ih1 + n0,
            &g_gi1[0][0] + m0 * G3 + n0, G3, HH, 0, As, Ws);
}

// GRU layer-1 elementwise + logits + gumbel sampling: one batch row per block.
__global__ __launch_bounds__(NTHR) void k_gate1_sample(
    int p, int t, const float* __restrict__ w_out,
    const float* __restrict__ b_out, float* __restrict__ out) {
  __shared__ __align__(16) float s_h[HH];
  __shared__ float s_log[32];
  __shared__ float s_score[32];
  const int q = p ^ 1;
  const int b = blockIdx.x;
  const int tid = threadIdx.x;
  const int j = tid << 2;

  const float* __restrict__ gi = g_gi1[b];
  const float* __restrict__ gh = g_gh1[p][b];
  f4 ir = *(const f4*)&gi[j];
  f4 iz = *(const f4*)&gi[j + HH];
  f4 in_ = *(const f4*)&gi[j + 2 * HH];
  f4 hr = *(const f4*)&gh[j];
  f4 hz = *(const f4*)&gh[j + HH];
  f4 hn = *(const f4*)&gh[j + 2 * HH];
  f4 hp = *(const f4*)&g_h1[p][b][j];
  f4 ho;
#pragma unroll
  for (int c = 0; c < 4; ++c)
    ho[c] = gru_h(ir[c], hr[c], iz[c], hz[c], in_[c], hn[c], hp[c]);
  *(f4*)&g_h1[q][b][j] = ho;
  *(f4*)&s_h[j] = ho;
  __syncthreads();

  // logits: 32 v-slots x 8 lanes, each lane sums 128 elements
  const int v = tid >> 3, ks = tid & 7;
  float part = 0.f;
  if (v < VV) {
    const float* __restrict__ wrow = w_out + v * HH + ks * 128;
    const float* __restrict__ hh = s_h + ks * 128;
#pragma unroll 8
    for (int i = 0; i < 128; i += 4) {
      f4 wv = *(const f4*)&wrow[i];
      f4 hv = *(const f4*)&hh[i];
      part += hv[0] * wv[0] + hv[1] * wv[1] + hv[2] * wv[2] + hv[3] * wv[3];
    }
  }
  part += __shfl_xor(part, 1);
  part += __shfl_xor(part, 2);
  part += __shfl_xor(part, 4);
  if (v < VV && ks == 0) s_log[v] = part;
  __syncthreads();

  if (tid < VV) {
    float logit = s_log[tid] + b_out[tid];
    out[(size_t)b * (TT * VV) + (size_t)t * VV + tid] = logit;
    // JAX partitionable threefry: key_t = tf((0,42),(0,t)); bits = x^y
    uint2 kt = tf2x32(0u, 42u, 0u, (unsigned)t);
    uint2 rr = tf2x32(kt.x, kt.y, 0u, (unsigned)(b * VV + tid));
    unsigned bits = rr.x ^ rr.y;
    float uf = __uint_as_float((bits >> 9) | 0x3f800000u) - 1.0f;
    if (uf <= 0.0f) uf = 1.17549435e-38f;  // finfo(f32).tiny
    s_score[tid] = logit - logf(-logf(uf));
  }
  __syncthreads();
  if (tid == 0) {
    float best = s_score[0];
    int bv = 0;
    for (int vv = 1; vv < VV; ++vv) {
      float s = s_score[vv];
      if (s > best) { best = s; bv = vv; }  // strict >: first max
    }
    g_tok[q][b] = bv;
    out[TOKBASE + (size_t)b * TT + t] = (float)bv;
  }
}

// Off-critical-path: gh0' = h0n@w_hh0^T ; gh1' = h1n@w_hh1^T  (384 tiles)
__global__ __launch_bounds__(NTHR) void k_hh(
    int p, const float* __restrict__ w_hh0, const float* __restrict__ b_hh0,
    const float* __restrict__ w_hh1, const float* __restrict__ b_hh1) {
  __shared__ __align__(16) float As[BM][KT + 4];
  __shared__ __align__(16) float Ws[KT][BN + 4];
  const int q = p ^ 1;
  const int bid = blockIdx.x;
  int u = (bid < 192) ? bid : bid - 192;
  int m0 = (u / 48) * BM, n0 = (u % 48) * BN;
  if (bid < 192) {
    gemm_unit(&g_h0[q][0][0] + m0 * HH, HH, BM, w_hh0 + n0 * HH, HH, b_hh0 + n0,
              &g_gh0[q][0][0] + m0 * G3 + n0, G3, HH, 0, As, Ws);
  } else {
    gemm_unit(&g_h1[q][0][0] + m0 * HH, HH, BM, w_hh1 + n0 * HH, HH, b_hh1 + n0,
              &g_gh1[q][0][0] + m0 * G3 + n0, G3, HH, 0, As, Ws);
  }
}

extern "C" void kernel_launch(void* const* d_in, const int* in_sizes, int n_in,
                              void* d_out, int out_size, void* d_ws, size_t ws_size,
                              hipStream_t stream) {
  (void)in_sizes; (void)n_in; (void)d_ws; (void)ws_size; (void)out_size;
  const float* z     = (const float*)d_in[0];
  const float* emb   = (const float*)d_in[1];
  const float* w_zh  = (const float*)d_in[2];
  const float* b_zh  = (const float*)d_in[3];
  const float* w_ih0 = (const float*)d_in[4];
  const float* w_hh0 = (const float*)d_in[5];
  const float* b_ih0 = (const float*)d_in[6];
  const float* b_hh0 = (const float*)d_in[7];
  const float* w_ih1 = (const float*)d_in[8];
  const float* w_hh1 = (const float*)d_in[9];
  const float* b_ih1 = (const float*)d_in[10];
  const float* b_hh1 = (const float*)d_in[11];
  const float* w_out = (const float*)d_in[12];
  const float* b_out = (const float*)d_in[13];
  float* out = (float*)d_out;

  k_setup1<<<dim3(177), dim3(NTHR), 0, stream>>>(z, w_zh, b_zh, emb, w_ih0, b_ih0);
  k_setup2<<<dim3(384), dim3(NTHR), 0, stream>>>(w_hh0, b_hh0, w_hh1, b_hh1);

  for (int t = 0; t < TT; ++t) {
    int p = t & 1;
    k_gate0<<<dim3(BB), dim3(NTHR), 0, stream>>>(p);
    k_gi1<<<dim3(192), dim3(NTHR), 0, stream>>>(p, w_ih1, b_ih1);
    k_gate1_sample<<<dim3(BB), dim3(NTHR), 0, stream>>>(p, t, w_out, b_out, out);
    k_hh<<<dim3(384), dim3(NTHR), 0, stream>>>(p, w_hh0, b_hh0, w_hh1, b_hh1);
  }
}